// Round 11
// baseline (275.153 us; speedup 1.0000x reference)
//
#include <hip/hip_runtime.h>
#include <math.h>

#define NH 4
#define NF 64
#define NM 32
#define NT 8  // nodes per block in k_proj (8 => ~50 VGPR, no spill)

__device__ __forceinline__ float softplusf(float v){ return fmaxf(v, 0.f) + log1pf(expf(-fabsf(v))); }
__device__ __forceinline__ float sigmoidf_(float v){ return 1.f / (1.f + expf(-v)); }

// ---------------- K0: zero deg + cursor ----------------
__global__ void k_zero(int* __restrict__ z, int n) {
  int i = blockIdx.x * blockDim.x + threadIdx.x;
  if (i < n) z[i] = 0;
}

// ---------------- K0b: degree count ----------------
__global__ void k_count(const int* __restrict__ ei, int* __restrict__ deg, int E) {
  int e = blockIdx.x * blockDim.x + threadIdx.x;
  if (e < E) atomicAdd(&deg[ei[E + e]], 1);
}

// ---------------- K1: fused node pass (all 3 matrices, NT=8 nodes/block) ----------------
// block = 256 = 4 heads x 64 cols. Each xs float4 broadcast feeds 12 FMAs.
// pt layout: [n][g][8], rows 0..3 = rp heads, 4..7 = tp heads.
__global__ __launch_bounds__(256)
void k_proj(const float* __restrict__ x,
            const float* __restrict__ Wp, const float* __restrict__ Wr, const float* __restrict__ Wt,
            const float* __restrict__ rsc, const float* __restrict__ tsc,
            const float* __restrict__ dW1, const float* __restrict__ db1,
            const float* __restrict__ dw2, const float* __restrict__ db2,
            const float* __restrict__ tW1, const float* __restrict__ tb1,
            const float* __restrict__ tw2, const float* __restrict__ tb2,
            const float* __restrict__ rdls, const float* __restrict__ rtb,
            float* __restrict__ pt,
            float* __restrict__ sr, float* __restrict__ st,
            float* __restrict__ doff, float* __restrict__ toff, int N) {
  int n0 = blockIdx.x * NT;
  int tid = threadIdx.x;
  int h = tid >> 6, g = tid & 63;
  __shared__ float xs[NT][NF];        // 2 KB
  __shared__ float eps[NT][NH][NF];   // 8 KB

  if (tid < NT * NF / 4) {
    int n = (tid * 4) >> 6, f = (tid * 4) & 63;
    float4 v = make_float4(0.f, 0.f, 0.f, 0.f);
    if (n0 + n < N) v = *(const float4*)(x + (size_t)(n0 + n) * NF + f);
    *(float4*)&xs[n][f] = v;
  }
  __syncthreads();

  const float* Wph = Wp + (size_t)h * NF * NF;
  const float* Wrh = Wr + (size_t)h * NF * NF;
  const float* Wth = Wt + (size_t)h * NF * NF;
  float accp[NT], accr[NT], acct[NT];
  #pragma unroll
  for (int n = 0; n < NT; ++n) { accp[n] = 0.f; accr[n] = 0.f; acct[n] = 0.f; }

  for (int f0 = 0; f0 < NF; f0 += 4) {
    float wp0 = Wph[(f0 + 0) * NF + g], wp1 = Wph[(f0 + 1) * NF + g],
          wp2 = Wph[(f0 + 2) * NF + g], wp3 = Wph[(f0 + 3) * NF + g];
    float wr0 = Wrh[(f0 + 0) * NF + g], wr1 = Wrh[(f0 + 1) * NF + g],
          wr2 = Wrh[(f0 + 2) * NF + g], wr3 = Wrh[(f0 + 3) * NF + g];
    float wt0 = Wth[(f0 + 0) * NF + g], wt1 = Wth[(f0 + 1) * NF + g],
          wt2 = Wth[(f0 + 2) * NF + g], wt3 = Wth[(f0 + 3) * NF + g];
    #pragma unroll
    for (int n = 0; n < NT; ++n) {
      float4 xv = *(const float4*)&xs[n][f0];
      accp[n] += xv.x * wp0 + xv.y * wp1 + xv.z * wp2 + xv.w * wp3;
      accr[n] += xv.x * wr0 + xv.y * wr1 + xv.z * wr2 + xv.w * wr3;
      acct[n] += xv.x * wt0 + xv.y * wt1 + xv.z * wt2 + xv.w * wt3;
    }
  }

  // write rp/tp into pt, stash ep into LDS
  #pragma unroll
  for (int n = 0; n < NT; ++n) {
    if (n0 + n < N) {
      size_t b = ((size_t)(n0 + n) * NF + g) * 8;
      pt[b + h]      = accr[n];
      pt[b + NH + h] = acct[n];
    }
    eps[n][h][g] = accp[n];
  }

  // sr/st per-head dot products
  float rs = rsc[h * NF + g], ts = tsc[h * NF + g];
  for (int n = 0; n < NT; ++n) {
    float a = accp[n] * rs, b = accp[n] * ts;
    for (int off = 32; off; off >>= 1) { a += __shfl_xor(a, off); b += __shfl_xor(b, off); }
    if (g == 0 && n0 + n < N) { sr[(n0 + n) * NH + h] = a; st[(n0 + n) * NH + h] = b; }
  }
  __syncthreads();

  // MLPs: lanes 0..31 decay, 32..63 temp
  int m = g & 31;
  bool isTemp = (g >= 32);
  const float* W1 = isTemp ? tW1 : dW1;
  float bias = isTemp ? tb1[h * NM + m] : db1[h * NM + m];
  float w2v  = isTemp ? tw2[h * NM + m] : dw2[h * NM + m];
  float accm[NT];
  #pragma unroll
  for (int n = 0; n < NT; ++n) accm[n] = bias;
  for (int f0 = 0; f0 < NF; f0 += 4) {
    float w0 = W1[(h * NF + f0 + 0) * NM + m];
    float w1 = W1[(h * NF + f0 + 1) * NM + m];
    float w2_ = W1[(h * NF + f0 + 2) * NM + m];
    float w3 = W1[(h * NF + f0 + 3) * NM + m];
    #pragma unroll
    for (int n = 0; n < NT; ++n) {
      float4 ev = *(const float4*)&eps[n][h][f0];
      accm[n] += ev.x * w0 + ev.y * w1 + ev.z * w2_ + ev.w * w3;
    }
  }
  for (int n = 0; n < NT; ++n) {
    float a = accm[n];
    float p = a * sigmoidf_(a) * w2v;  // silu * w2
    for (int off = 16; off; off >>= 1) p += __shfl_xor(p, off);
    if (m == 0 && n0 + n < N) {
      if (!isTemp) doff[(n0 + n) * NH + h] = p + db2[h] + softplusf(rdls[h]);
      else         toff[(n0 + n) * NH + h] = p + tb2[h] + rtb[h];
    }
  }
}

// ---------------- K2: exclusive prefix scan of degrees (single block) ----------------
__global__ void k_scan(const int* __restrict__ deg, int* __restrict__ start, int N) {
  __shared__ int sd[1024];
  __shared__ int sbase;
  int tid = threadIdx.x;
  if (tid == 0) sbase = 0;
  __syncthreads();
  int nc = (N + 1023) >> 10;
  for (int c = 0; c < nc; ++c) {
    int i = (c << 10) + tid;
    int v = (i < N) ? deg[i] : 0;
    sd[tid] = v;
    __syncthreads();
    for (int off = 1; off < 1024; off <<= 1) {
      int t = (tid >= off) ? sd[tid - off] : 0;
      __syncthreads();
      sd[tid] += t;
      __syncthreads();
    }
    int base = sbase;
    if (i < N) start[i] = base + sd[tid] - v;
    int total = sd[1023];
    __syncthreads();
    if (tid == 0) sbase = base + total;
    __syncthreads();
  }
  if (tid == 0) start[N] = sbase;
}

// ---------------- K3: per-edge logits + gate, written in CSR order ----------------
__global__ void k_edge(const int* __restrict__ ei, const float* __restrict__ elen,
                       const float4* __restrict__ sr4, const float4* __restrict__ st4,
                       const float4* __restrict__ doff4, const float4* __restrict__ toff4,
                       const float* __restrict__ rtw,
                       const float* __restrict__ mixb, const float* __restrict__ mixs,
                       const int* __restrict__ start, int* __restrict__ cursor,
                       float4* __restrict__ crl, float4* __restrict__ ctl, float4* __restrict__ cgv,
                       int* __restrict__ snd, int E) {
  int e = blockIdx.x * blockDim.x + threadIdx.x;
  if (e >= E) return;
  int s = ei[e], r = ei[E + e];
  float len = elen[e];
  int slot = start[r] + atomicAdd(&cursor[r], 1);
  float4 a = sr4[s], b = sr4[r], c = st4[s], d = st4[r], dof = doff4[r], tof = toff4[r];
  const float* ap = (const float*)&a; const float* bp = (const float*)&b;
  const float* cp = (const float*)&c; const float* dp = (const float*)&d;
  const float* dofp = (const float*)&dof; const float* tofp = (const float*)&tof;
  float rlv[NH], tlv[NH], gv[NH];
  #pragma unroll
  for (int h = 0; h < NH; ++h) {
    float temp = softplusf(tofp[h] + rtw[h] * len);
    rlv[h] = (ap[h] - bp[h] - dofp[h] * len) / (temp + 1e-4f);
    tlv[h] = cp[h] - dp[h];
    gv[h] = sigmoidf_(mixb[h] + mixs[h] * len);
  }
  crl[slot] = make_float4(rlv[0], rlv[1], rlv[2], rlv[3]);
  ctl[slot] = make_float4(tlv[0], tlv[1], tlv[2], tlv[3]);
  cgv[slot] = make_float4(gv[0], gv[1], gv[2], gv[3]);
  snd[slot] = s;
}

// ---------------- K4: per-receiver softmax + gather-aggregate + Wout + residual ----------------
__global__ __launch_bounds__(256)
void k_aggout(const int* __restrict__ start, const int* __restrict__ snd,
              const float4* __restrict__ crl, const float4* __restrict__ ctl, const float4* __restrict__ cgv,
              const float* __restrict__ pt, const float* __restrict__ x,
              const float* __restrict__ Wout, float* __restrict__ out, int N) {
  __shared__ float wout_s[NF * NF];
  __shared__ float coef_s[4][64][8];
  __shared__ int   snd_s[4][64];
  __shared__ float am_s[4][NF];
  int tid = threadIdx.x;
  {
    const float4* w4 = (const float4*)Wout;
    float4* s4 = (float4*)wout_s;
    for (int i = tid; i < NF * NF / 4; i += 256) s4[i] = w4[i];
  }
  __syncthreads();   // only block-wide barrier; everything after is wave-local
  int w = tid >> 6, g = tid & 63;
  int n = blockIdx.x * 4 + w;
  if (n >= N) return;
  int i0 = start[n], i1 = start[n + 1];

  // pass A: per-head max (edge-parallel, lane = edge)
  float rm[NH] = {-1e30f, -1e30f, -1e30f, -1e30f};
  float tm[NH] = {-1e30f, -1e30f, -1e30f, -1e30f};
  for (int i = i0 + g; i < i1; i += 64) {
    float4 rv = crl[i], tv = ctl[i];
    const float* rp_ = (const float*)&rv; const float* tp_ = (const float*)&tv;
    #pragma unroll
    for (int h = 0; h < NH; ++h) { rm[h] = fmaxf(rm[h], rp_[h]); tm[h] = fmaxf(tm[h], tp_[h]); }
  }
  #pragma unroll
  for (int off = 32; off; off >>= 1)
    #pragma unroll
    for (int h = 0; h < NH; ++h) {
      rm[h] = fmaxf(rm[h], __shfl_xor(rm[h], off));
      tm[h] = fmaxf(tm[h], __shfl_xor(tm[h], off));
    }

  // pass B: per-head exp-sum
  float rs_[NH] = {0.f, 0.f, 0.f, 0.f}, ts_[NH] = {0.f, 0.f, 0.f, 0.f};
  for (int i = i0 + g; i < i1; i += 64) {
    float4 rv = crl[i], tv = ctl[i];
    const float* rp_ = (const float*)&rv; const float* tp_ = (const float*)&tv;
    #pragma unroll
    for (int h = 0; h < NH; ++h) { rs_[h] += expf(rp_[h] - rm[h]); ts_[h] += expf(tp_[h] - tm[h]); }
  }
  #pragma unroll
  for (int off = 32; off; off >>= 1)
    #pragma unroll
    for (int h = 0; h < NH; ++h) { rs_[h] += __shfl_xor(rs_[h], off); ts_[h] += __shfl_xor(ts_[h], off); }
  #pragma unroll
  for (int h = 0; h < NH; ++h) { rs_[h] = 1.f / (rs_[h] + 1e-9f); ts_[h] = 1.f / (ts_[h] + 1e-9f); }

  // pass C: coefficients (lane=edge) + gather-aggregate (lane=feature)
  float acc = 0.f;
  float sc1[NH] = {0.f, 0.f, 0.f, 0.f}, sc2[NH] = {0.f, 0.f, 0.f, 0.f};
  for (int base = i0; base < i1; base += 64) {
    int i = base + g;
    if (i < i1) {
      float4 rv = crl[i], tv = ctl[i], gv = cgv[i];
      const float* rp_ = (const float*)&rv; const float* tp_ = (const float*)&tv;
      const float* gp_ = (const float*)&gv;
      #pragma unroll
      for (int h = 0; h < NH; ++h) {
        float ar = expf(rp_[h] - rm[h]) * rs_[h];
        float at = expf(tp_[h] - tm[h]) * ts_[h];
        float gg = gp_[h];
        float ba = gg * ar + (1.f - gg) * at;
        float c1 = ba * gg, c2 = ba * (1.f - gg);
        coef_s[w][g][h] = c1; coef_s[w][g][4 + h] = c2;
        sc1[h] += c1; sc2[h] += c2;
      }
      snd_s[w][g] = snd[i];
    }
    int cnt = min(64, i1 - base);
    for (int j = 0; j < cnt; ++j) {
      int s = snd_s[w][j];
      const float4* b4 = (const float4*)(pt + ((size_t)s * NF + g) * 8);
      float4 rpv = b4[0], tpv = b4[1];
      const float* rpp = (const float*)&rpv; const float* tpp = (const float*)&tpv;
      #pragma unroll
      for (int h = 0; h < NH; ++h)
        acc += coef_s[w][j][h] * rpp[h] + coef_s[w][j][4 + h] * tpp[h];
    }
  }
  // reduce coefficient sums across the wave (each lane held its own edges' share)
  #pragma unroll
  for (int off = 32; off; off >>= 1)
    #pragma unroll
    for (int h = 0; h < NH; ++h) { sc1[h] += __shfl_xor(sc1[h], off); sc2[h] += __shfl_xor(sc2[h], off); }

  const float4* bn4 = (const float4*)(pt + ((size_t)n * NF + g) * 8);
  float4 rpn = bn4[0], tpn = bn4[1];
  const float* rnp = (const float*)&rpn; const float* tnp = (const float*)&tpn;
  #pragma unroll
  for (int h = 0; h < NH; ++h) acc -= sc1[h] * rnp[h] + sc2[h] * tnp[h];
  acc *= (1.f / NH);

  am_s[w][g] = acc;   // wave-local LDS; no block barrier needed
  float o = x[(size_t)n * NF + g];
  #pragma unroll 8
  for (int f = 0; f < NF; ++f) o += am_s[w][f] * wout_s[f * NF + g];
  out[(size_t)n * NF + g] = o;
}

extern "C" void kernel_launch(void* const* d_in, const int* in_sizes, int n_in,
                              void* d_out, int out_size, void* d_ws, size_t ws_size,
                              hipStream_t stream) {
  const float* x    = (const float*)d_in[0];
  const int*   ei   = (const int*)d_in[1];
  // d_in[2] = edge_vec, unused by the reference
  const float* elen = (const float*)d_in[3];
  const float* Wp   = (const float*)d_in[4];
  const float* Wr   = (const float*)d_in[5];
  const float* Wt   = (const float*)d_in[6];
  const float* rsc  = (const float*)d_in[7];
  const float* tsc  = (const float*)d_in[8];
  const float* rdls = (const float*)d_in[9];
  const float* rtb  = (const float*)d_in[10];
  const float* rtw  = (const float*)d_in[11];
  const float* mixb = (const float*)d_in[12];
  const float* mixs = (const float*)d_in[13];
  const float* dW1  = (const float*)d_in[14];
  const float* db1  = (const float*)d_in[15];
  const float* dw2  = (const float*)d_in[16];
  const float* db2  = (const float*)d_in[17];
  const float* tW1  = (const float*)d_in[18];
  const float* tb1  = (const float*)d_in[19];
  const float* tw2  = (const float*)d_in[20];
  const float* tb2  = (const float*)d_in[21];
  const float* Wout = (const float*)d_in[22];

  int N = in_sizes[0] / NF;
  int E = in_sizes[3];

  float* p = (float*)d_ws;
  float* pt   = p; p += (size_t)N * NF * 8;   // [n][g][8]
  float* sr   = p; p += (size_t)N * NH;
  float* st   = p; p += (size_t)N * NH;
  float* doff = p; p += (size_t)N * NH;
  float* toff = p; p += (size_t)N * NH;
  float* crl  = p; p += (size_t)E * NH;       // CSR-ordered radial logits
  float* ctl  = p; p += (size_t)E * NH;       // CSR-ordered tangential logits
  float* cgv  = p; p += (size_t)E * NH;       // CSR-ordered mix gate
  int* snd    = (int*)p; p += E;              // CSR-ordered sender ids
  int* deg    = (int*)p; p += N;
  int* cursor = (int*)p; p += N;
  int* startp = (int*)p; p += N + 1;

  // K0: zero deg + cursor (contiguous)
  k_zero<<<(2 * N + 255) / 256, 256, 0, stream>>>(deg, 2 * N);
  // K0b: degree count
  k_count<<<(E + 255) / 256, 256, 0, stream>>>(ei, deg, E);
  // K1: fused node pass
  k_proj<<<(N + NT - 1) / NT, 256, 0, stream>>>(x, Wp, Wr, Wt, rsc, tsc, dW1, db1, dw2, db2,
                                                tW1, tb1, tw2, tb2, rdls, rtb,
                                                pt, sr, st, doff, toff, N);
  // K2: scan degrees -> CSR starts
  k_scan<<<1, 1024, 0, stream>>>(deg, startp, N);
  // K3: per-edge logits into CSR slots
  k_edge<<<(E + 255) / 256, 256, 0, stream>>>(ei, elen, (const float4*)sr, (const float4*)st,
                                              (const float4*)doff, (const float4*)toff,
                                              rtw, mixb, mixs, startp, cursor,
                                              (float4*)crl, (float4*)ctl, (float4*)cgv, snd, E);
  // K4: softmax + aggregate + output
  k_aggout<<<(N + 3) / 4, 256, 0, stream>>>(startp, snd, (const float4*)crl, (const float4*)ctl,
                                            (const float4*)cgv, pt, x, Wout, (float*)d_out, N);
}

// Round 12
// 246.077 us; speedup vs baseline: 1.1182x; 1.1182x over previous
//
#include <hip/hip_runtime.h>
#include <math.h>

#define NH 4
#define NF 64
#define NM 32
#define NT 16  // nodes per block in k_proj

__device__ __forceinline__ float softplusf(float v){ return fmaxf(v, 0.f) + log1pf(expf(-fabsf(v))); }
__device__ __forceinline__ float sigmoidf_(float v){ return 1.f / (1.f + expf(-v)); }

// ---------------- K0: zero deg + cursor ----------------
__global__ void k_zero(int* __restrict__ z, int n) {
  int i = blockIdx.x * blockDim.x + threadIdx.x;
  if (i < n) z[i] = 0;
}

// ---------------- K0b: degree count ----------------
__global__ void k_count(const int* __restrict__ ei, int* __restrict__ deg, int E) {
  int e = blockIdx.x * blockDim.x + threadIdx.x;
  if (e < E) atomicAdd(&deg[ei[E + e]], 1);
}

// ---------------- K1: tiled node pass (split: blockIdx.y = matrix) ----------------
// grid = (ceil(N/NT), 3); block = 256 = 4 heads x 64 cols.
// R6 structure (105us, occ 39%) + float4 xs reads: per f0 = 4 weight loads +
// NT ds_read_b128 + 4*NT FMAs (ds:FMA = 1:4). ~30 live VGPRs.
// mat 0: ep (LDS) + sr/st + decay/temp MLPs. mat 1/2: rp/tp into pt[n][g][8].
__global__ __launch_bounds__(256)
void k_proj(const float* __restrict__ x,
            const float* __restrict__ Wp, const float* __restrict__ Wr, const float* __restrict__ Wt,
            const float* __restrict__ rsc, const float* __restrict__ tsc,
            const float* __restrict__ dW1, const float* __restrict__ db1,
            const float* __restrict__ dw2, const float* __restrict__ db2,
            const float* __restrict__ tW1, const float* __restrict__ tb1,
            const float* __restrict__ tw2, const float* __restrict__ tb2,
            const float* __restrict__ rdls, const float* __restrict__ rtb,
            float* __restrict__ pt,
            float* __restrict__ sr, float* __restrict__ st,
            float* __restrict__ doff, float* __restrict__ toff, int N) {
  int n0 = blockIdx.x * NT;
  int mat = blockIdx.y;
  int tid = threadIdx.x;
  int h = tid >> 6, g = tid & 63;
  __shared__ float xs[NT][NF];        // 4 KB
  __shared__ float eps[NT][NH][NF];   // 16 KB (only used by mat 0)

  {
    // 256 float4 = whole x tile; thread i loads one float4
    int n = (tid * 4) >> 6, f = (tid * 4) & 63;
    float4 v = make_float4(0.f, 0.f, 0.f, 0.f);
    if (n0 + n < N) v = *(const float4*)(x + (size_t)(n0 + n) * NF + f);
    *(float4*)&xs[n][f] = v;
  }
  __syncthreads();

  const float* W = (mat == 0 ? Wp : (mat == 1 ? Wr : Wt)) + (size_t)h * NF * NF;
  float acc[NT];
  #pragma unroll
  for (int n = 0; n < NT; ++n) acc[n] = 0.f;

  for (int f0 = 0; f0 < NF; f0 += 4) {
    float w0 = W[(f0 + 0) * NF + g];
    float w1 = W[(f0 + 1) * NF + g];
    float w2 = W[(f0 + 2) * NF + g];
    float w3 = W[(f0 + 3) * NF + g];
    #pragma unroll
    for (int n = 0; n < NT; ++n) {
      float4 xv = *(const float4*)&xs[n][f0];
      acc[n] += xv.x * w0 + xv.y * w1 + xv.z * w2 + xv.w * w3;
    }
  }

  if (mat != 0) {
    // rp -> rows 0..3, tp -> rows 4..7 of pt[n][g][8]
    int row = (mat - 1) * NH + h;
    #pragma unroll
    for (int n = 0; n < NT; ++n)
      if (n0 + n < N) pt[(((size_t)(n0 + n)) * NF + g) * 8 + row] = acc[n];
    return;
  }

  // mat == 0: ep path
  #pragma unroll
  for (int n = 0; n < NT; ++n) eps[n][h][g] = acc[n];

  float rs = rsc[h * NF + g], ts = tsc[h * NF + g];
  for (int n = 0; n < NT; ++n) {
    float a = acc[n] * rs, b = acc[n] * ts;
    for (int off = 32; off; off >>= 1) { a += __shfl_xor(a, off); b += __shfl_xor(b, off); }
    if (g == 0 && n0 + n < N) { sr[(n0 + n) * NH + h] = a; st[(n0 + n) * NH + h] = b; }
  }
  __syncthreads();

  // MLPs: lanes 0..31 decay, 32..63 temp; float4 eps reads
  int m = g & 31;
  bool isTemp = (g >= 32);
  const float* W1 = isTemp ? tW1 : dW1;
  float bias = isTemp ? tb1[h * NM + m] : db1[h * NM + m];
  float w2v  = isTemp ? tw2[h * NM + m] : dw2[h * NM + m];
  float accm[NT];
  #pragma unroll
  for (int n = 0; n < NT; ++n) accm[n] = bias;
  for (int f0 = 0; f0 < NF; f0 += 4) {
    float w0 = W1[(h * NF + f0 + 0) * NM + m];
    float w1 = W1[(h * NF + f0 + 1) * NM + m];
    float w2_ = W1[(h * NF + f0 + 2) * NM + m];
    float w3 = W1[(h * NF + f0 + 3) * NM + m];
    #pragma unroll
    for (int n = 0; n < NT; ++n) {
      float4 ev = *(const float4*)&eps[n][h][f0];
      accm[n] += ev.x * w0 + ev.y * w1 + ev.z * w2_ + ev.w * w3;
    }
  }
  for (int n = 0; n < NT; ++n) {
    float a = accm[n];
    float p = a * sigmoidf_(a) * w2v;  // silu * w2
    for (int off = 16; off; off >>= 1) p += __shfl_xor(p, off);
    if (m == 0 && n0 + n < N) {
      if (!isTemp) doff[(n0 + n) * NH + h] = p + db2[h] + softplusf(rdls[h]);
      else         toff[(n0 + n) * NH + h] = p + tb2[h] + rtb[h];
    }
  }
}

// ---------------- K2: exclusive prefix scan of degrees (single block) ----------------
__global__ void k_scan(const int* __restrict__ deg, int* __restrict__ start, int N) {
  __shared__ int sd[1024];
  __shared__ int sbase;
  int tid = threadIdx.x;
  if (tid == 0) sbase = 0;
  __syncthreads();
  int nc = (N + 1023) >> 10;
  for (int c = 0; c < nc; ++c) {
    int i = (c << 10) + tid;
    int v = (i < N) ? deg[i] : 0;
    sd[tid] = v;
    __syncthreads();
    for (int off = 1; off < 1024; off <<= 1) {
      int t = (tid >= off) ? sd[tid - off] : 0;
      __syncthreads();
      sd[tid] += t;
      __syncthreads();
    }
    int base = sbase;
    if (i < N) start[i] = base + sd[tid] - v;
    int total = sd[1023];
    __syncthreads();
    if (tid == 0) sbase = base + total;
    __syncthreads();
  }
  if (tid == 0) start[N] = sbase;
}

// ---------------- K3: per-edge logits + gate, written in CSR order ----------------
__global__ void k_edge(const int* __restrict__ ei, const float* __restrict__ elen,
                       const float4* __restrict__ sr4, const float4* __restrict__ st4,
                       const float4* __restrict__ doff4, const float4* __restrict__ toff4,
                       const float* __restrict__ rtw,
                       const float* __restrict__ mixb, const float* __restrict__ mixs,
                       const int* __restrict__ start, int* __restrict__ cursor,
                       float4* __restrict__ crl, float4* __restrict__ ctl, float4* __restrict__ cgv,
                       int* __restrict__ snd, int E) {
  int e = blockIdx.x * blockDim.x + threadIdx.x;
  if (e >= E) return;
  int s = ei[e], r = ei[E + e];
  float len = elen[e];
  int slot = start[r] + atomicAdd(&cursor[r], 1);
  float4 a = sr4[s], b = sr4[r], c = st4[s], d = st4[r], dof = doff4[r], tof = toff4[r];
  const float* ap = (const float*)&a; const float* bp = (const float*)&b;
  const float* cp = (const float*)&c; const float* dp = (const float*)&d;
  const float* dofp = (const float*)&dof; const float* tofp = (const float*)&tof;
  float rlv[NH], tlv[NH], gv[NH];
  #pragma unroll
  for (int h = 0; h < NH; ++h) {
    float temp = softplusf(tofp[h] + rtw[h] * len);
    rlv[h] = (ap[h] - bp[h] - dofp[h] * len) / (temp + 1e-4f);
    tlv[h] = cp[h] - dp[h];
    gv[h] = sigmoidf_(mixb[h] + mixs[h] * len);
  }
  crl[slot] = make_float4(rlv[0], rlv[1], rlv[2], rlv[3]);
  ctl[slot] = make_float4(tlv[0], tlv[1], tlv[2], tlv[3]);
  cgv[slot] = make_float4(gv[0], gv[1], gv[2], gv[3]);
  snd[slot] = s;
}

// ---------------- K4: per-receiver softmax + gather-aggregate + Wout + residual ----------------
__global__ __launch_bounds__(256)
void k_aggout(const int* __restrict__ start, const int* __restrict__ snd,
              const float4* __restrict__ crl, const float4* __restrict__ ctl, const float4* __restrict__ cgv,
              const float* __restrict__ pt, const float* __restrict__ x,
              const float* __restrict__ Wout, float* __restrict__ out, int N) {
  __shared__ float wout_s[NF * NF];
  __shared__ float coef_s[4][64][8];
  __shared__ int   snd_s[4][64];
  __shared__ float am_s[4][NF];
  int tid = threadIdx.x;
  {
    const float4* w4 = (const float4*)Wout;
    float4* s4 = (float4*)wout_s;
    for (int i = tid; i < NF * NF / 4; i += 256) s4[i] = w4[i];
  }
  __syncthreads();   // only block-wide barrier; everything after is wave-local
  int w = tid >> 6, g = tid & 63;
  int n = blockIdx.x * 4 + w;
  if (n >= N) return;
  int i0 = start[n], i1 = start[n + 1];

  // pass A: per-head max (edge-parallel, lane = edge)
  float rm[NH] = {-1e30f, -1e30f, -1e30f, -1e30f};
  float tm[NH] = {-1e30f, -1e30f, -1e30f, -1e30f};
  for (int i = i0 + g; i < i1; i += 64) {
    float4 rv = crl[i], tv = ctl[i];
    const float* rp_ = (const float*)&rv; const float* tp_ = (const float*)&tv;
    #pragma unroll
    for (int h = 0; h < NH; ++h) { rm[h] = fmaxf(rm[h], rp_[h]); tm[h] = fmaxf(tm[h], tp_[h]); }
  }
  #pragma unroll
  for (int off = 32; off; off >>= 1)
    #pragma unroll
    for (int h = 0; h < NH; ++h) {
      rm[h] = fmaxf(rm[h], __shfl_xor(rm[h], off));
      tm[h] = fmaxf(tm[h], __shfl_xor(tm[h], off));
    }

  // pass B: per-head exp-sum
  float rs_[NH] = {0.f, 0.f, 0.f, 0.f}, ts_[NH] = {0.f, 0.f, 0.f, 0.f};
  for (int i = i0 + g; i < i1; i += 64) {
    float4 rv = crl[i], tv = ctl[i];
    const float* rp_ = (const float*)&rv; const float* tp_ = (const float*)&tv;
    #pragma unroll
    for (int h = 0; h < NH; ++h) { rs_[h] += expf(rp_[h] - rm[h]); ts_[h] += expf(tp_[h] - tm[h]); }
  }
  #pragma unroll
  for (int off = 32; off; off >>= 1)
    #pragma unroll
    for (int h = 0; h < NH; ++h) { rs_[h] += __shfl_xor(rs_[h], off); ts_[h] += __shfl_xor(ts_[h], off); }
  #pragma unroll
  for (int h = 0; h < NH; ++h) { rs_[h] = 1.f / (rs_[h] + 1e-9f); ts_[h] = 1.f / (ts_[h] + 1e-9f); }

  // pass C: coefficients (lane=edge) + gather-aggregate (lane=feature)
  float acc = 0.f;
  float sc1[NH] = {0.f, 0.f, 0.f, 0.f}, sc2[NH] = {0.f, 0.f, 0.f, 0.f};
  for (int base = i0; base < i1; base += 64) {
    int i = base + g;
    if (i < i1) {
      float4 rv = crl[i], tv = ctl[i], gv = cgv[i];
      const float* rp_ = (const float*)&rv; const float* tp_ = (const float*)&tv;
      const float* gp_ = (const float*)&gv;
      #pragma unroll
      for (int h = 0; h < NH; ++h) {
        float ar = expf(rp_[h] - rm[h]) * rs_[h];
        float at = expf(tp_[h] - tm[h]) * ts_[h];
        float gg = gp_[h];
        float ba = gg * ar + (1.f - gg) * at;
        float c1 = ba * gg, c2 = ba * (1.f - gg);
        coef_s[w][g][h] = c1; coef_s[w][g][4 + h] = c2;
        sc1[h] += c1; sc2[h] += c2;
      }
      snd_s[w][g] = snd[i];
    }
    int cnt = min(64, i1 - base);
    for (int j = 0; j < cnt; ++j) {
      int s = snd_s[w][j];
      const float4* b4 = (const float4*)(pt + ((size_t)s * NF + g) * 8);
      float4 rpv = b4[0], tpv = b4[1];
      const float* rpp = (const float*)&rpv; const float* tpp = (const float*)&tpv;
      #pragma unroll
      for (int h = 0; h < NH; ++h)
        acc += coef_s[w][j][h] * rpp[h] + coef_s[w][j][4 + h] * tpp[h];
    }
  }
  // reduce coefficient sums across the wave (each lane held its own edges' share)
  #pragma unroll
  for (int off = 32; off; off >>= 1)
    #pragma unroll
    for (int h = 0; h < NH; ++h) { sc1[h] += __shfl_xor(sc1[h], off); sc2[h] += __shfl_xor(sc2[h], off); }

  const float4* bn4 = (const float4*)(pt + ((size_t)n * NF + g) * 8);
  float4 rpn = bn4[0], tpn = bn4[1];
  const float* rnp = (const float*)&rpn; const float* tnp = (const float*)&tpn;
  #pragma unroll
  for (int h = 0; h < NH; ++h) acc -= sc1[h] * rnp[h] + sc2[h] * tnp[h];
  acc *= (1.f / NH);

  am_s[w][g] = acc;   // wave-local LDS; no block barrier needed
  float o = x[(size_t)n * NF + g];
  #pragma unroll 8
  for (int f = 0; f < NF; ++f) o += am_s[w][f] * wout_s[f * NF + g];
  out[(size_t)n * NF + g] = o;
}

extern "C" void kernel_launch(void* const* d_in, const int* in_sizes, int n_in,
                              void* d_out, int out_size, void* d_ws, size_t ws_size,
                              hipStream_t stream) {
  const float* x    = (const float*)d_in[0];
  const int*   ei   = (const int*)d_in[1];
  // d_in[2] = edge_vec, unused by the reference
  const float* elen = (const float*)d_in[3];
  const float* Wp   = (const float*)d_in[4];
  const float* Wr   = (const float*)d_in[5];
  const float* Wt   = (const float*)d_in[6];
  const float* rsc  = (const float*)d_in[7];
  const float* tsc  = (const float*)d_in[8];
  const float* rdls = (const float*)d_in[9];
  const float* rtb  = (const float*)d_in[10];
  const float* rtw  = (const float*)d_in[11];
  const float* mixb = (const float*)d_in[12];
  const float* mixs = (const float*)d_in[13];
  const float* dW1  = (const float*)d_in[14];
  const float* db1  = (const float*)d_in[15];
  const float* dw2  = (const float*)d_in[16];
  const float* db2  = (const float*)d_in[17];
  const float* tW1  = (const float*)d_in[18];
  const float* tb1  = (const float*)d_in[19];
  const float* tw2  = (const float*)d_in[20];
  const float* tb2  = (const float*)d_in[21];
  const float* Wout = (const float*)d_in[22];

  int N = in_sizes[0] / NF;
  int E = in_sizes[3];

  float* p = (float*)d_ws;
  float* pt   = p; p += (size_t)N * NF * 8;   // [n][g][8]
  float* sr   = p; p += (size_t)N * NH;
  float* st   = p; p += (size_t)N * NH;
  float* doff = p; p += (size_t)N * NH;
  float* toff = p; p += (size_t)N * NH;
  float* crl  = p; p += (size_t)E * NH;       // CSR-ordered radial logits
  float* ctl  = p; p += (size_t)E * NH;       // CSR-ordered tangential logits
  float* cgv  = p; p += (size_t)E * NH;       // CSR-ordered mix gate
  int* snd    = (int*)p; p += E;              // CSR-ordered sender ids
  int* deg    = (int*)p; p += N;
  int* cursor = (int*)p; p += N;
  int* startp = (int*)p; p += N + 1;

  // K0: zero deg + cursor (contiguous)
  k_zero<<<(2 * N + 255) / 256, 256, 0, stream>>>(deg, 2 * N);
  // K0b: degree count
  k_count<<<(E + 255) / 256, 256, 0, stream>>>(ei, deg, E);
  // K1: tiled node pass (split by matrix)
  {
    dim3 grid((N + NT - 1) / NT, 3);
    k_proj<<<grid, 256, 0, stream>>>(x, Wp, Wr, Wt, rsc, tsc, dW1, db1, dw2, db2,
                                     tW1, tb1, tw2, tb2, rdls, rtb,
                                     pt, sr, st, doff, toff, N);
  }
  // K2: scan degrees -> CSR starts
  k_scan<<<1, 1024, 0, stream>>>(deg, startp, N);
  // K3: per-edge logits into CSR slots
  k_edge<<<(E + 255) / 256, 256, 0, stream>>>(ei, elen, (const float4*)sr, (const float4*)st,
                                              (const float4*)doff, (const float4*)toff,
                                              rtw, mixb, mixs, startp, cursor,
                                              (float4*)crl, (float4*)ctl, (float4*)cgv, snd, E);
  // K4: softmax + aggregate + output
  k_aggout<<<(N + 3) / 4, 256, 0, stream>>>(startp, snd, (const float4*)crl, (const float4*)ctl,
                                            (const float4*)cgv, pt, x, Wout, (float*)d_out, N);
}